// Round 2
// baseline (2457.126 us; speedup 1.0000x reference)
//
#include <hip/hip_runtime.h>
#include <hip/hip_bf16.h>

#define IN_F 32
#define HID 64
#define OUTF 16
#define C1 67                      // 2*IN + 3
#define ORD_NEG_INF 0x007FFFFFu    // ordenc(-inf)

// monotone float -> uint map so unsigned max == float max
__device__ __forceinline__ unsigned ordenc(float v) {
  unsigned b = __float_as_uint(v);
  return (b & 0x80000000u) ? ~b : (b | 0x80000000u);
}
__device__ __forceinline__ float orddec(unsigned u) {
  unsigned b = (u & 0x80000000u) ? (u & 0x7FFFFFFFu) : ~u;
  return __uint_as_float(b);
}

__global__ __launch_bounds__(256) void init_agg_kernel(unsigned* __restrict__ agg, int n) {
  int i = blockIdx.x * blockDim.x + threadIdx.x;
  if (i < n) agg[i] = ORD_NEG_INF;
}

// One wave processes 4 edges per iteration.
// Lane k owns output channel k; W1/W2 columns live in registers (131 VGPRs).
// tmp (67 inputs) and h (64 hidden) staged in LDS transposed [c][edge] so the
// inner loops are 1 broadcast ds_read_b128 + 4 v_fmac per c.
__global__ __launch_bounds__(256) void edge_kernel(
    const float* __restrict__ x,           // [N, 32]
    const int* __restrict__ ei,            // [2, E] int32: src row then dst row
    const float* __restrict__ ea,          // [E, 3]
    const float* __restrict__ W1,          // [67, 64]
    const float* __restrict__ b1,          // [64]
    const float* __restrict__ W2,          // [64, 64]
    const float* __restrict__ b2,          // [64]
    unsigned* __restrict__ agg,            // [N, 64] ord-encoded
    int E)
{
  __shared__ float tmps[4][C1 + 1][4];  // [wave][c][edge] ~4.3 KB
  __shared__ float hs[4][HID][4];       // [wave][j][edge] 4 KB

  const int wave = threadIdx.x >> 6;
  const int lane = threadIdx.x & 63;

  float w1r[C1];
#pragma unroll
  for (int c = 0; c < C1; ++c) w1r[c] = W1[c * HID + lane];
  float w2r[HID];
#pragma unroll
  for (int j = 0; j < HID; ++j) w2r[j] = W2[j * HID + lane];
  const float b1v = b1[lane];
  const float b2v = b2[lane];

  const int gwave = (blockIdx.x << 2) | wave;
  const int stride = gridDim.x << 4;          // gridDim.x * 4 waves * 4 edges
  const int iters = (E + stride - 1) / stride; // uniform across ALL waves

  for (int it = 0; it < iters; ++it) {
    const int e0 = (gwave << 2) + it * stride;
    int dstv[4];
    // ---- stage tmp for up to 4 edges ----
#pragma unroll
    for (int i = 0; i < 4; ++i) {
      int e = e0 + i;
      if (e < E) {
        int s = ei[e];
        int d = ei[E + e];
        dstv[i] = d;
        if (lane < IN_F) {
          tmps[wave][lane][i] = x[d * IN_F + lane];                    // x_i
        } else {
          int c = lane - IN_F;
          tmps[wave][lane][i] = x[s * IN_F + c] - x[d * IN_F + c];     // x_j - x_i
        }
        if (lane < 3) tmps[wave][2 * IN_F + lane][i] = ea[e * 3 + lane];
      } else {
        dstv[i] = -1;
      }
    }
    __syncthreads();

    // ---- layer 1: h = relu(tmp @ W1 + b1) ----
    float a0 = b1v, a1 = b1v, a2 = b1v, a3 = b1v;
#pragma unroll
    for (int c = 0; c < C1; ++c) {
      const float4 t = *(const float4*)&tmps[wave][c][0];  // broadcast
      a0 = fmaf(t.x, w1r[c], a0);
      a1 = fmaf(t.y, w1r[c], a1);
      a2 = fmaf(t.z, w1r[c], a2);
      a3 = fmaf(t.w, w1r[c], a3);
    }
    float4 h;
    h.x = fmaxf(a0, 0.f); h.y = fmaxf(a1, 0.f);
    h.z = fmaxf(a2, 0.f); h.w = fmaxf(a3, 0.f);
    __syncthreads();
    *(float4*)&hs[wave][lane][0] = h;
    __syncthreads();

    // ---- layer 2: msg = h @ W2 + b2 ----
    float m0 = b2v, m1 = b2v, m2 = b2v, m3 = b2v;
#pragma unroll
    for (int j = 0; j < HID; ++j) {
      const float4 hh = *(const float4*)&hs[wave][j][0];   // broadcast
      m0 = fmaf(hh.x, w2r[j], m0);
      m1 = fmaf(hh.y, w2r[j], m1);
      m2 = fmaf(hh.z, w2r[j], m2);
      m3 = fmaf(hh.w, w2r[j], m3);
    }

    // ---- max-scatter (coalesced 64-lane atomic per edge) ----
    if (dstv[0] >= 0) atomicMax(&agg[dstv[0] * HID + lane], ordenc(m0));
    if (dstv[1] >= 0) atomicMax(&agg[dstv[1] * HID + lane], ordenc(m1));
    if (dstv[2] >= 0) atomicMax(&agg[dstv[2] * HID + lane], ordenc(m2));
    if (dstv[3] >= 0) atomicMax(&agg[dstv[3] * HID + lane], ordenc(m3));
  }
}

// 16 nodes per block: decode agg (empty -> 0), out = sigmoid(agg @ Wo + bo)
__global__ __launch_bounds__(256) void out_kernel(
    const unsigned* __restrict__ agg,
    const float* __restrict__ Wo,  // [64, 16]
    const float* __restrict__ bo,  // [16]
    float* __restrict__ out,       // [N, 16]
    int N)
{
  __shared__ float Wos[HID * OUTF];
  __shared__ float bos[OUTF];
  __shared__ float aggs[16][HID + 1];

  for (int i = threadIdx.x; i < HID * OUTF; i += 256) Wos[i] = Wo[i];
  if (threadIdx.x < OUTF) bos[threadIdx.x] = bo[threadIdx.x];
  __syncthreads();

  const int nodeBase = blockIdx.x * 16;
  {
    int ln = threadIdx.x >> 4;
    int k0 = (threadIdx.x & 15) * 4;
    int n = nodeBase + ln;
    if (n < N) {
      const uint4 u = *(const uint4*)&agg[n * HID + k0];
      aggs[ln][k0 + 0] = (u.x == ORD_NEG_INF) ? 0.f : orddec(u.x);
      aggs[ln][k0 + 1] = (u.y == ORD_NEG_INF) ? 0.f : orddec(u.y);
      aggs[ln][k0 + 2] = (u.z == ORD_NEG_INF) ? 0.f : orddec(u.z);
      aggs[ln][k0 + 3] = (u.w == ORD_NEG_INF) ? 0.f : orddec(u.w);
    }
  }
  __syncthreads();
  {
    int ln = threadIdx.x >> 4;
    int o = threadIdx.x & 15;
    int n = nodeBase + ln;
    if (n < N) {
      float acc = bos[o];
#pragma unroll
      for (int k = 0; k < HID; ++k) acc = fmaf(aggs[ln][k], Wos[k * OUTF + o], acc);
      out[n * OUTF + o] = 1.f / (1.f + __expf(-acc));
    }
  }
}

extern "C" void kernel_launch(void* const* d_in, const int* in_sizes, int n_in,
                              void* d_out, int out_size, void* d_ws, size_t ws_size,
                              hipStream_t stream) {
  const float* x  = (const float*)d_in[0];
  const int*   ei = (const int*)d_in[1];
  const float* ea = (const float*)d_in[2];
  const float* W1 = (const float*)d_in[3];
  const float* b1 = (const float*)d_in[4];
  const float* W2 = (const float*)d_in[5];
  const float* b2 = (const float*)d_in[6];
  const float* Wo = (const float*)d_in[7];
  const float* bo = (const float*)d_in[8];
  float* out = (float*)d_out;

  const int N = in_sizes[0] / IN_F;   // 50000
  const int E = in_sizes[1] / 2;      // 1600000
  unsigned* agg = (unsigned*)d_ws;    // N*64*4 = 12.8 MB

  const int ntot = N * HID;
  init_agg_kernel<<<(ntot + 255) / 256, 256, 0, stream>>>(agg, ntot);
  edge_kernel<<<2048, 256, 0, stream>>>(x, ei, ea, W1, b1, W2, b2, agg, E);
  out_kernel<<<(N + 15) / 16, 256, 0, stream>>>(agg, Wo, bo, out, N);
}